// Round 17
// baseline (325.905 us; speedup 1.0000x reference)
//
#include <hip/hip_runtime.h>

// XOR chain = inclusive prefix-XOR along axis 0 of [S=4096, B=8192] int32.
// Round 17: CONCURRENT producer/consumer blocks in ONE dispatch.
// R16 measured: pure-read kernel ~1.9 TB/s is the bottleneck; write path does
// 6.7 TB/s; the restore-copy proves concurrent read+write streams hit ~6.4
// total. So: 256 READER blocks stream 128 MiB -> packed bit-table (8 MiB),
// while 256 WRITER blocks concurrently consume it (L2 loads only) and NT-
// stream the 128 MiB output. Both HBM directions busy from T~=0.
//  - table entry u64 = {w, ~w}: self-validating (0xAA poison fails hi==~lo,
//    real words always pass), atomic u64 stores => no tearing, no fences,
//    no init kernel, single dispatch.
//  - seed parity is linear over XOR: writer keeps running fold F; seed bit
//    = popc(F)&1 applied as whole-word mask. 5 shift-XORs scan 32 rows.
//  - readers walk 4 chunks sequentially => chunks publish at T/4..T; write
//    tail after last publish ~32 MB ~= 5 us. All 512 blocks co-resident =>
//    deadlock-free (readers never wait; writers wait on lower-idx readers).

#define S 4096
#define B4 2048               // v4u column-groups per row
#define TPB 256
#define NCHUNK 128            // 32-row chunks
#define CPR 4                 // chunks per reader/writer range
#define NRG (NCHUNK / CPR)    // 32 ranges
#define NCT 8                 // column tiles
#define NBLK (NCT * NRG * 2)  // 512 blocks: even=reader, odd=writer

typedef unsigned int v4u __attribute__((ext_vector_type(4)));
typedef unsigned long long u64;

__device__ __forceinline__ bool ok64(u64 v) {
    return (unsigned)(v >> 32) == ~(unsigned)v;
}
__device__ __forceinline__ unsigned scan32(unsigned x) {
    x ^= x << 1; x ^= x << 2; x ^= x << 4; x ^= x << 8; x ^= x << 16;
    return x;
}

__global__ __launch_bounds__(TPB) void xor_pc(
        const v4u* __restrict__ in, v4u* __restrict__ out,
        u64* __restrict__ tab) {
    const int idx  = blockIdx.x;
    const int g    = idx >> 1;
    const int ct   = g & (NCT - 1);
    const int c0   = (g >> 3) * CPR;
    const int colg = ct * TPB + threadIdx.x;

    if ((idx & 1) == 0) {
        // ---------------- READER: stream 4 chunks, publish packed words ----
        for (int c = c0; c < c0 + CPR; ++c) {
            const v4u* p = in + (size_t)c * 32 * B4 + colg;
            unsigned w0 = 0u, w1 = 0u, w2 = 0u, w3 = 0u;
#pragma unroll
            for (int b = 0; b < 4; ++b) {
                v4u v[8];
#pragma unroll
                for (int j = 0; j < 8; ++j) v[j] = p[(size_t)(b * 8 + j) * B4];
#pragma unroll
                for (int j = 0; j < 8; ++j) {
                    const int r = b * 8 + j;
                    w0 |= (v[j].x & 1u) << r;
                    w1 |= (v[j].y & 1u) << r;
                    w2 |= (v[j].z & 1u) << r;
                    w3 |= (v[j].w & 1u) << r;
                }
            }
            u64* e = tab + ((size_t)c * B4 + colg) * 4;
            __hip_atomic_store(&e[0], ((u64)~w0 << 32) | w0,
                               __ATOMIC_RELAXED, __HIP_MEMORY_SCOPE_AGENT);
            __hip_atomic_store(&e[1], ((u64)~w1 << 32) | w1,
                               __ATOMIC_RELAXED, __HIP_MEMORY_SCOPE_AGENT);
            __hip_atomic_store(&e[2], ((u64)~w2 << 32) | w2,
                               __ATOMIC_RELAXED, __HIP_MEMORY_SCOPE_AGENT);
            __hip_atomic_store(&e[3], ((u64)~w3 << 32) | w3,
                               __ATOMIC_RELAXED, __HIP_MEMORY_SCOPE_AGENT);
        }
    } else {
        // ---------------- WRITER: fold prefix, scan, expand, NT stream ----
        unsigned F0 = 0u, F1 = 0u, F2 = 0u, F3 = 0u;
        // Prefold chunks [0, c0) with batched validity polling (L2 loads).
        int c = 0;
        while (c < c0) {
            int n = c0 - c; if (n > 4) n = 4;
            u64 a[16];
            for (int j = 0; j < n; ++j) {
                u64* e = tab + ((size_t)(c + j) * B4 + colg) * 4;
                for (int k = 0; k < 4; ++k)
                    a[j * 4 + k] = __hip_atomic_load(&e[k], __ATOMIC_RELAXED,
                                                     __HIP_MEMORY_SCOPE_AGENT);
            }
            bool good = true;
            for (int j = 0; j < n * 4; ++j) good &= ok64(a[j]);
            if (good) {
                for (int j = 0; j < n; ++j) {
                    F0 ^= (unsigned)a[j * 4 + 0];
                    F1 ^= (unsigned)a[j * 4 + 1];
                    F2 ^= (unsigned)a[j * 4 + 2];
                    F3 ^= (unsigned)a[j * 4 + 3];
                }
                c += n;
            } else {
                __builtin_amdgcn_s_sleep(2);
            }
        }
        // Consume own range: poll, scan, seed, expand, store.
        for (int cc = c0; cc < c0 + CPR; ++cc) {
            u64* e = tab + ((size_t)cc * B4 + colg) * 4;
            u64 a0, a1, a2, a3;
            for (;;) {
                a0 = __hip_atomic_load(&e[0], __ATOMIC_RELAXED,
                                       __HIP_MEMORY_SCOPE_AGENT);
                a1 = __hip_atomic_load(&e[1], __ATOMIC_RELAXED,
                                       __HIP_MEMORY_SCOPE_AGENT);
                a2 = __hip_atomic_load(&e[2], __ATOMIC_RELAXED,
                                       __HIP_MEMORY_SCOPE_AGENT);
                a3 = __hip_atomic_load(&e[3], __ATOMIC_RELAXED,
                                       __HIP_MEMORY_SCOPE_AGENT);
                if (ok64(a0) && ok64(a1) && ok64(a2) && ok64(a3)) break;
                __builtin_amdgcn_s_sleep(2);
            }
            const unsigned w0 = (unsigned)a0, w1 = (unsigned)a1;
            const unsigned w2 = (unsigned)a2, w3 = (unsigned)a3;
            const unsigned f0 = scan32(w0) ^ (0u - (unsigned)(__popc(F0) & 1));
            const unsigned f1 = scan32(w1) ^ (0u - (unsigned)(__popc(F1) & 1));
            const unsigned f2 = scan32(w2) ^ (0u - (unsigned)(__popc(F2) & 1));
            const unsigned f3 = scan32(w3) ^ (0u - (unsigned)(__popc(F3) & 1));
            v4u* q = out + (size_t)cc * 32 * B4 + colg;
#pragma unroll 8
            for (int r = 0; r < 32; ++r) {
                v4u ov = (v4u){(f0 >> r) & 1u, (f1 >> r) & 1u,
                               (f2 >> r) & 1u, (f3 >> r) & 1u};
                __builtin_nontemporal_store(ov, &q[(size_t)r * B4]);
            }
            F0 ^= w0; F1 ^= w1; F2 ^= w2; F3 ^= w3;
        }
    }
}

extern "C" void kernel_launch(void* const* d_in, const int* in_sizes, int n_in,
                              void* d_out, int out_size, void* d_ws, size_t ws_size,
                              hipStream_t stream) {
    const v4u* in = (const v4u*)d_in[0];
    v4u* out = (v4u*)d_out;
    u64* tab = (u64*)d_ws;   // 8 MiB packed table, poison-self-validating

    xor_pc<<<NBLK, TPB, 0, stream>>>(in, out, tab);
}